// Round 8
// baseline (411.098 us; speedup 1.0000x reference)
//
#include <hip/hip_runtime.h>
#include <hip/hip_bf16.h>
#include <stdint.h>

// ---------------------------------------------------------------------------
// MultiHeadAttention fused forward, bf16-MFMA pipeline.
// B=4, T=2048, D=1024, H=16, HD=64.  Input order: x, Wk, Wq, Wv, Wp, bp (fp32).
// R8: XCD-aware block remap (same-input blocks -> same linear%8 -> same XCD
//     L2) in attn + both GEMMs; V-frag register hoist across grps; attn
//     occupancy 5 blocks/CU.
// ---------------------------------------------------------------------------

typedef __bf16 bf16x8 __attribute__((ext_vector_type(8)));
typedef float floatx4 __attribute__((ext_vector_type(4)));
typedef unsigned short ushort_t;
typedef unsigned short ushortx8 __attribute__((ext_vector_type(8)));
typedef unsigned short ushortx4 __attribute__((ext_vector_type(4)));
typedef short shortx4 __attribute__((ext_vector_type(4)));

#define MFMA16(a, b, c) __builtin_amdgcn_mfma_f32_16x16x32_bf16((a), (b), (c), 0, 0, 0)
#define MFMA16K16(a, b, c) __builtin_amdgcn_mfma_f32_16x16x16bf16_1k((a), (b), (c), 0, 0, 0)
#define EXP2F(x) __builtin_amdgcn_exp2f(x)

static __device__ __forceinline__ ushort_t f2bfu(float f) {
  union { float f; unsigned u; } v; v.f = f;
  unsigned r = v.u + 0x7FFFu + ((v.u >> 16) & 1u);  // RNE
  return (ushort_t)(r >> 16);
}

// pack two floats' bf16-truncations into one dword: (hi<<16)|lo
static __device__ __forceinline__ unsigned pack_bf2(float lo, float hi) {
  return __builtin_amdgcn_perm(__float_as_uint(hi), __float_as_uint(lo), 0x07060302);
}

// async 16B global -> LDS DMA (dest is wave-uniform base + lane*16)
static __device__ __forceinline__ void gl_lds16(const void* g, void* l) {
  __builtin_amdgcn_global_load_lds(
      (const __attribute__((address_space(1))) void*)g,
      (__attribute__((address_space(3))) void*)l, 16, 0, 0);
}

// ---- fp32 -> bf16 cast, all 5 tensors in one launch (dst regions contiguous)
__global__ void cvt_all(const float* __restrict__ x,  const float* __restrict__ wk,
                        const float* __restrict__ wq, const float* __restrict__ wv,
                        const float* __restrict__ wp, ushortx4* __restrict__ dst) {
  const int i = blockIdx.x * blockDim.x + threadIdx.x;  // float4 units
  const float4* src; int off;
  if (i < 2097152) { src = (const float4*)x; off = i; }
  else {
    const int r = i - 2097152;
    const int sel = r >> 18;                 // 262144 float4 per weight
    off = r & 262143;
    src = (const float4*)(sel == 0 ? wk : sel == 1 ? wq : sel == 2 ? wv : wp);
  }
  const float4 f = src[off];
  ushortx4 o;
  o[0] = f2bfu(f.x); o[1] = f2bfu(f.y); o[2] = f2bfu(f.z); o[3] = f2bfu(f.w);
  dst[i] = o;
}

// ---------------------------------------------------------------------------
// QKV GEMM: C[m,n] = sum_k X[m,k] * W[n,k]   (M=8192, N=1024, K=1024)
// m97 structure + XOR bank swizzle. z=0->Q, z=1->K (both [B,H,T,64]),
// z=2->V^T ([B,H,64,T], vectorized 8B epilogue).
// XCD remap: same m0 (X row-slice) -> same linear%8 -> same XCD L2.
// ---------------------------------------------------------------------------
__global__ __launch_bounds__(256) void gemm_qkv(
    const ushort_t* __restrict__ X,
    const ushort_t* __restrict__ Wq, const ushort_t* __restrict__ Wk,
    const ushort_t* __restrict__ Wv,
    ushort_t* __restrict__ qb, ushort_t* __restrict__ kb, ushort_t* __restrict__ vtb)
{
  // XCD-aware relabel of (m0, n0, z): grid (64,8,3) flat L in [0,1536)
  const int L = (int)(blockIdx.x + 64 * (blockIdx.y + 8 * blockIdx.z));
  const int rr = L & 7, mm = L >> 3;           // mm 0..191
  const int m0 = (rr + 8 * (mm & 7)) * 128;    // 64 m-tiles, same tile -> same rr
  const int rest = mm >> 3;                    // 0..23
  const int n0 = (rest & 7) * 128;
  const int z = rest >> 3;

  const ushort_t* Bm = (z == 0) ? Wq : (z == 1) ? Wk : Wv;
  __shared__ ushort_t Al[128 * 64];
  __shared__ ushort_t Bl[128 * 64];
  const int tid = threadIdx.x;
  const int w = tid >> 6, lane = tid & 63, g = lane >> 4, c = lane & 15;
  const int wm = w >> 1, wn = w & 1;
  const int cswz = c & 7;

  floatx4 acc[4][4];
  const floatx4 zero4 = {0.f, 0.f, 0.f, 0.f};
#pragma unroll
  for (int i = 0; i < 4; ++i)
#pragma unroll
    for (int j = 0; j < 4; ++j) acc[i][j] = zero4;

  const int srow = tid >> 3;
  const int gsw  = ((tid & 7) ^ (srow & 7)) * 8;  // swizzled source chunk (shorts)

  for (int k0 = 0; k0 < 1024; k0 += 64) {
#pragma unroll
    for (int p = 0; p < 4; ++p) {
      const int row = p * 32 + srow;
      gl_lds16(&X [(size_t)(m0 + row) * 1024 + k0 + gsw], &Al[p * 2048 + tid * 8]);
      gl_lds16(&Bm[(size_t)(n0 + row) * 1024 + k0 + gsw], &Bl[p * 2048 + tid * 8]);
    }
    __syncthreads();
#pragma unroll
    for (int kk = 0; kk < 2; ++kk) {
      bf16x8 af[4], bfr[4];
#pragma unroll
      for (int i = 0; i < 4; ++i) {
        const int sw = ((kk * 4 + g) ^ cswz) * 8;
        af[i]  = *reinterpret_cast<const bf16x8*>(&Al[(wm * 64 + i * 16 + c) * 64 + sw]);
        bfr[i] = *reinterpret_cast<const bf16x8*>(&Bl[(wn * 64 + i * 16 + c) * 64 + sw]);
      }
#pragma unroll
      for (int i = 0; i < 4; ++i)
#pragma unroll
        for (int j = 0; j < 4; ++j)
          acc[i][j] = MFMA16(af[i], bfr[j], acc[i][j]);
    }
    __syncthreads();
  }

  // Epilogue: C/D layout row = g*4+r, col = c within each 16x16 tile.
#pragma unroll
  for (int i = 0; i < 4; ++i) {
#pragma unroll
    for (int j = 0; j < 4; ++j) {
      const int mbase = m0 + wm * 64 + i * 16 + g * 4;
      const int n = n0 + wn * 64 + j * 16 + c;
      const int h = n >> 6, d = n & 63;
      if (z == 2) {
        // V^T: [(bb*16+h)*64+d]*2048 + t, 4 consecutive t -> 8B store
        const int bb = mbase >> 11, t = mbase & 2047;
        ushortx4 pk;
#pragma unroll
        for (int r = 0; r < 4; ++r) pk[r] = f2bfu(acc[i][j][r]);
        *reinterpret_cast<ushortx4*>(&vtb[(size_t)((bb * 16 + h) * 64 + d) * 2048 + t]) = pk;
      } else {
        ushort_t* ob = (z == 0) ? qb : kb;
#pragma unroll
        for (int r = 0; r < 4; ++r) {
          const int m = mbase + r;
          const int bb = m >> 11, t = m & 2047;
          ob[(size_t)((bb * 16 + h) * 2048 + t) * 64 + d] = f2bfu(acc[i][j][r]);
        }
      }
    }
  }
}

// ---------------------------------------------------------------------------
// Flash attention (causal), register-resident P^T.
// XCD remap: all 16 j-blocks of one (b,h) -> same linear%8 -> same XCD, so
// that (b,h)'s K/V (512 KB) stays L2-resident (8 bh/XCD ~ 4 MB = L2 size).
// Block j of (b,h): q-tiles j and 31-j; wave w owns 16 rows of each.
// Per 128-key staged iter: S^T = K*Q^T (C/D: lane=q, reg=key) -> P^T in
// registers == B-operand of mfma 16x16x16 -> O^T += V^T*P^T, V-frags hoisted
// into registers across grps. No P LDS round-trip; deferred l-reduction.
// ---------------------------------------------------------------------------
__global__ __launch_bounds__(256, 5) void attn_kernel(
    const ushort_t* __restrict__ qbuf, const ushort_t* __restrict__ kbuf,
    const ushort_t* __restrict__ vtbuf, ushort_t* __restrict__ obuf)
{
  // XCD-aware relabel: grid (16,16,4) flat L in [0,1024)
  const int L = (int)(blockIdx.x + 16 * (blockIdx.y + 16 * blockIdx.z));
  const int rr = L & 7, mm = L >> 3;        // mm 0..127
  const int j = mm >> 3;                    // q-tile pair index 0..15
  const int bhl = rr * 8 + (mm & 7);        // 0..63, same bh -> same rr
  const int h = bhl & 15, b = bhl >> 4;

  const int tid = threadIdx.x, w = tid >> 6, lane = tid & 63, g = lane >> 4, c = lane & 15;

  __shared__ ushort_t Kl[128 * 64];       // [key][d], XOR-swizzled 8-chunk rows
  __shared__ ushort_t Vl[64 * 128];       // [d][key], XOR-swizzled 16-chunk rows

  const size_t bh = (size_t)(b * 16 + h);
  const ushort_t* kb_bh = kbuf + bh * 2048 * 64;
  const ushort_t* vt_bh = vtbuf + bh * 64 * 2048;
  const ushort_t* qb_bh = qbuf + bh * 2048 * 64;

  const int rb0 = j * 64 + w * 16;           // grp 0 q-rows (diag tile j)
  const int rb1 = (31 - j) * 64 + w * 16;    // grp 1 q-rows (diag tile 31-j)

  // Q B-frags (x32): B[n=q=lane&15][k=d=quad*8+j]: contiguous 16B loads
  bf16x8 aq0[2], aq1[2];
  {
    const ushort_t* qp0 = qb_bh + (size_t)(rb0 + c) * 64;
    aq0[0] = *reinterpret_cast<const bf16x8*>(qp0 + g * 8);
    aq0[1] = *reinterpret_cast<const bf16x8*>(qp0 + 32 + g * 8);
    const ushort_t* qp1 = qb_bh + (size_t)(rb1 + c) * 64;
    aq1[0] = *reinterpret_cast<const bf16x8*>(qp1 + g * 8);
    aq1[1] = *reinterpret_cast<const bf16x8*>(qp1 + 32 + g * 8);
  }

  // O^T accumulators: [grp][td] tile, lane holds d = td*16+g*4+r, q = rb+c
  floatx4 oacc0[4], oacc1[4];
  float l0 = 0.f, l1 = 0.f;
  const floatx4 zero4 = {0.f, 0.f, 0.f, 0.f};
#pragma unroll
  for (int td = 0; td < 4; ++td) { oacc0[td] = zero4; oacc1[td] = zero4; }

  // staging index helpers
  const int krow_s = tid >> 3;                       // K: 32 rows per p-iter
  const int kgsw   = ((tid & 7) ^ (krow_s & 7)) * 8; // K source chunk (shorts)
  const int vrow_s = tid >> 4;                       // V: 16 rows per p-iter
  const int vgsw   = ((tid & 15) ^ (vrow_s & 15)) * 8;

  const float SCALE = 0.18033688011112042f;  // 0.125 * log2(e)

  const int n128 = (33 - j) >> 1;  // 128-key iters (covers subtiles 0..31-j)
  for (int kt = 0; kt < n128; ++kt) {
    const int key0 = kt * 128;
#pragma unroll
    for (int p = 0; p < 4; ++p) {
      const int kr = p * 32 + krow_s;
      gl_lds16(&kb_bh[(size_t)(key0 + kr) * 64 + kgsw], &Kl[p * 2048 + tid * 8]);
      const int vr = p * 16 + vrow_s;
      gl_lds16(&vt_bh[(size_t)vr * 2048 + key0 + vgsw], &Vl[p * 2048 + tid * 8]);
    }
    __syncthreads();

#pragma unroll
    for (int s = 0; s < 2; ++s) {
      const int ti = 2 * kt + s;       // 64-key subtile index
      if (ti > 31 - j) continue;       // uniform: no grp left for this subtile
      const int key0s = ti * 64;

      // Hoist V-frags for this subtile into registers (shared by both grps)
      shortx4 vf[4][4];
#pragma unroll
      for (int t4 = 0; t4 < 4; ++t4) {
        const int cc = s * 8 + t4 * 2 + (g >> 1);       // V key-chunk index
        const int ko = (g & 1) * 4;                      // within-chunk key
#pragma unroll
        for (int td = 0; td < 4; ++td)
          vf[t4][td] = *reinterpret_cast<const shortx4*>(
              &Vl[(td * 16 + c) * 128 + ((cc ^ c) & 15) * 8 + ko]);
      }

#pragma unroll
      for (int grp = 0; grp < 2; ++grp) {
        const int lim = (grp == 0) ? j : 31 - j;
        if (ti > lim) continue;        // uniform scalar branch
        const int rb = (grp == 0) ? rb0 : rb1;
        const bf16x8 b0 = (grp == 0) ? aq0[0] : aq1[0];
        const bf16x8 b1 = (grp == 0) ? aq0[1] : aq1[1];

        float pv[4][4];
#pragma unroll
        for (int t4 = 0; t4 < 4; ++t4) {
          // S^T tile: A = K-frag (m=key=lane&15 -> row key0s+t4*16+c)
          const int krow = s * 64 + t4 * 16 + c;
          const bf16x8 k0f = *reinterpret_cast<const bf16x8*>(&Kl[krow * 64 + ((g) ^ (c & 7)) * 8]);
          const bf16x8 k1f = *reinterpret_cast<const bf16x8*>(&Kl[krow * 64 + ((4 + g) ^ (c & 7)) * 8]);
          floatx4 sa = zero4;
          sa = MFMA16(k0f, b0, sa);
          sa = MFMA16(k1f, b1, sa);
          // C/D: lane c = q-col, reg r -> key = key0s + t4*16 + g*4 + r
          if (ti == lim) {             // diagonal tile: causal mask
            const int q = rb + c;
#pragma unroll
            for (int r = 0; r < 4; ++r) {
              const int key = key0s + t4 * 16 + g * 4 + r;
              const float e = EXP2F(sa[r] * SCALE);
              pv[t4][r] = (key <= q) ? e : 0.f;
            }
          } else {
#pragma unroll
            for (int r = 0; r < 4; ++r) pv[t4][r] = EXP2F(sa[r] * SCALE);
          }
        }
        // l partial (each lane's 16 values all belong to q = rb+c)
        float lsum = 0.f;
#pragma unroll
        for (int t4 = 0; t4 < 4; ++t4)
          lsum += (pv[t4][0] + pv[t4][1]) + (pv[t4][2] + pv[t4][3]);
        if (grp == 0) l0 += lsum; else l1 += lsum;

        // PV: O^T += V^T * P^T via mfma 16x16x16 (P^T regs ARE the B-frag)
#pragma unroll
        for (int t4 = 0; t4 < 4; ++t4) {
          union { unsigned u[2]; shortx4 v; } pk;
          pk.u[0] = pack_bf2(pv[t4][0], pv[t4][1]);
          pk.u[1] = pack_bf2(pv[t4][2], pv[t4][3]);
#pragma unroll
          for (int td = 0; td < 4; ++td) {
            if (grp == 0) oacc0[td] = MFMA16K16(vf[t4][td], pk.v, oacc0[td]);
            else          oacc1[td] = MFMA16K16(vf[t4][td], pk.v, oacc1[td]);
          }
        }
      }
    }
    __syncthreads();
  }

  // l: reduce across quads (q = c; partial per quad g) then normalize+store
#pragma unroll
  for (int grp = 0; grp < 2; ++grp) {
    float ls = (grp == 0) ? l0 : l1;
    ls += __shfl_xor(ls, 16, 64);
    ls += __shfl_xor(ls, 32, 64);
    const float inv = 1.f / ls;
    const int q = ((grp == 0) ? rb0 : rb1) + c;
    ushort_t* ob = &obuf[((size_t)(b * 2048 + q) * 16 + h) * 64];
#pragma unroll
    for (int td = 0; td < 4; ++td) {
      const floatx4 oa = (grp == 0) ? oacc0[td] : oacc1[td];
      ushortx4 pk;
#pragma unroll
      for (int r = 0; r < 4; ++r) pk[r] = f2bfu(oa[r] * inv);
      *reinterpret_cast<ushortx4*>(&ob[td * 16 + g * 4]) = pk;
    }
  }
}

// ---------------------------------------------------------------------------
// Output projection: out[m,n] = sum_k O[m,k] * Wp[n,k] + bp[n], fp32 out.
// XCD remap as in gemm_qkv.
// ---------------------------------------------------------------------------
__global__ __launch_bounds__(256) void gemm_proj(
    const ushort_t* __restrict__ A, const ushort_t* __restrict__ Wp,
    const float* __restrict__ bias, float* __restrict__ out)
{
  const int L = (int)(blockIdx.x + 64 * blockIdx.y);  // grid (64,8), L in [0,512)
  const int rr = L & 7, mm = L >> 3;                  // mm 0..63
  const int m0 = (rr + 8 * (mm & 7)) * 128;
  const int n0 = (mm >> 3) * 128;

  __shared__ ushort_t Al[128 * 64];
  __shared__ ushort_t Bl[128 * 64];
  const int tid = threadIdx.x;
  const int w = tid >> 6, lane = tid & 63, g = lane >> 4, c = lane & 15;
  const int wm = w >> 1, wn = w & 1;
  const int cswz = c & 7;

  floatx4 acc[4][4];
  const floatx4 zero4 = {0.f, 0.f, 0.f, 0.f};
#pragma unroll
  for (int i = 0; i < 4; ++i)
#pragma unroll
    for (int j = 0; j < 4; ++j) acc[i][j] = zero4;

  const int srow = tid >> 3;
  const int gsw  = ((tid & 7) ^ (srow & 7)) * 8;

  for (int k0 = 0; k0 < 1024; k0 += 64) {
#pragma unroll
    for (int p = 0; p < 4; ++p) {
      const int row = p * 32 + srow;
      gl_lds16(&A [(size_t)(m0 + row) * 1024 + k0 + gsw], &Al[p * 2048 + tid * 8]);
      gl_lds16(&Wp[(size_t)(n0 + row) * 1024 + k0 + gsw], &Bl[p * 2048 + tid * 8]);
    }
    __syncthreads();
#pragma unroll
    for (int kk = 0; kk < 2; ++kk) {
      bf16x8 af[4], bfr[4];
#pragma unroll
      for (int i = 0; i < 4; ++i) {
        const int sw = ((kk * 4 + g) ^ cswz) * 8;
        af[i]  = *reinterpret_cast<const bf16x8*>(&Al[(wm * 64 + i * 16 + c) * 64 + sw]);
        bfr[i] = *reinterpret_cast<const bf16x8*>(&Bl[(wn * 64 + i * 16 + c) * 64 + sw]);
      }
#pragma unroll
      for (int i = 0; i < 4; ++i)
#pragma unroll
        for (int j = 0; j < 4; ++j)
          acc[i][j] = MFMA16(af[i], bfr[j], acc[i][j]);
    }
    __syncthreads();
  }

#pragma unroll
  for (int i = 0; i < 4; ++i) {
#pragma unroll
    for (int j = 0; j < 4; ++j) {
      const int n = n0 + wn * 64 + j * 16 + c;
      const float bv = bias[n];
#pragma unroll
      for (int r = 0; r < 4; ++r) {
        const int m = m0 + wm * 64 + i * 16 + g * 4 + r;
        out[(size_t)m * 1024 + n] = acc[i][j][r] + bv;
      }
    }
  }
}

extern "C" void kernel_launch(void* const* d_in, const int* in_sizes, int n_in,
                              void* d_out, int out_size, void* d_ws, size_t ws_size,
                              hipStream_t stream) {
  const float* x  = (const float*)d_in[0];
  const float* Wk = (const float*)d_in[1];   // input order: x, Wk, Wq, Wv, Wp, bp
  const float* Wq = (const float*)d_in[2];
  const float* Wv = (const float*)d_in[3];
  const float* Wp = (const float*)d_in[4];
  const float* bp = (const float*)d_in[5];
  float* out = (float*)d_out;

  char* ws = (char*)d_ws;
  const size_t SZ_X = (size_t)8192 * 1024 * 2;  // 16 MB bf16
  const size_t SZ_W = (size_t)1024 * 1024 * 2;  //  2 MB bf16
  ushort_t* xb    = (ushort_t*)ws;  ws += SZ_X;  // xb..wpb contiguous (cvt_all dst)
  ushort_t* wkb   = (ushort_t*)ws;  ws += SZ_W;
  ushort_t* wqb   = (ushort_t*)ws;  ws += SZ_W;
  ushort_t* wvb   = (ushort_t*)ws;  ws += SZ_W;
  ushort_t* wpb   = (ushort_t*)ws;  ws += SZ_W;
  ushort_t* qbuf  = (ushort_t*)ws;  ws += SZ_X;
  ushort_t* kbuf  = (ushort_t*)ws;  ws += SZ_X;
  ushort_t* vtbuf = (ushort_t*)ws;  ws += SZ_X;
  ushort_t* obuf  = xb;  // x is consumed by gemm_qkv before attn writes obuf

  cvt_all<<<12288, 256, 0, stream>>>(x, Wk, Wq, Wv, Wp, (ushortx4*)xb);

  gemm_qkv<<<dim3(64, 8, 3), 256, 0, stream>>>(xb, wqb, wkb, wvb, qbuf, kbuf, vtbuf);
  attn_kernel<<<dim3(16, 16, 4), 256, 0, stream>>>(qbuf, kbuf, vtbuf, obuf);
  gemm_proj<<<dim3(64, 8), 256, 0, stream>>>(obuf, wpb, bp, out);
}

// Round 9
// 241.092 us; speedup vs baseline: 1.7052x; 1.7052x over previous
//
#include <hip/hip_runtime.h>
#include <hip/hip_bf16.h>
#include <stdint.h>

// ---------------------------------------------------------------------------
// MultiHeadAttention fused forward, bf16-MFMA pipeline.
// B=4, T=2048, D=1024, H=16, HD=64.  Input order: x, Wk, Wq, Wv, Wp, bp (fp32).
// R9: attn reverted to R7 body (lb(256,4), no V-frag hoist — R8's hoist +
//     lb(256,5) caused 616 MB scratch spill). XCD remap kept in all kernels
//     (GEMM side measured faster in R8).
// ---------------------------------------------------------------------------

typedef __bf16 bf16x8 __attribute__((ext_vector_type(8)));
typedef float floatx4 __attribute__((ext_vector_type(4)));
typedef unsigned short ushort_t;
typedef unsigned short ushortx8 __attribute__((ext_vector_type(8)));
typedef unsigned short ushortx4 __attribute__((ext_vector_type(4)));
typedef short shortx4 __attribute__((ext_vector_type(4)));

#define MFMA16(a, b, c) __builtin_amdgcn_mfma_f32_16x16x32_bf16((a), (b), (c), 0, 0, 0)
#define MFMA16K16(a, b, c) __builtin_amdgcn_mfma_f32_16x16x16bf16_1k((a), (b), (c), 0, 0, 0)
#define EXP2F(x) __builtin_amdgcn_exp2f(x)

static __device__ __forceinline__ ushort_t f2bfu(float f) {
  union { float f; unsigned u; } v; v.f = f;
  unsigned r = v.u + 0x7FFFu + ((v.u >> 16) & 1u);  // RNE
  return (ushort_t)(r >> 16);
}

// pack two floats' bf16-truncations into one dword: (hi<<16)|lo
static __device__ __forceinline__ unsigned pack_bf2(float lo, float hi) {
  return __builtin_amdgcn_perm(__float_as_uint(hi), __float_as_uint(lo), 0x07060302);
}

// async 16B global -> LDS DMA (dest is wave-uniform base + lane*16)
static __device__ __forceinline__ void gl_lds16(const void* g, void* l) {
  __builtin_amdgcn_global_load_lds(
      (const __attribute__((address_space(1))) void*)g,
      (__attribute__((address_space(3))) void*)l, 16, 0, 0);
}

// ---- fp32 -> bf16 cast, all 5 tensors in one launch (dst regions contiguous)
__global__ void cvt_all(const float* __restrict__ x,  const float* __restrict__ wk,
                        const float* __restrict__ wq, const float* __restrict__ wv,
                        const float* __restrict__ wp, ushortx4* __restrict__ dst) {
  const int i = blockIdx.x * blockDim.x + threadIdx.x;  // float4 units
  const float4* src; int off;
  if (i < 2097152) { src = (const float4*)x; off = i; }
  else {
    const int r = i - 2097152;
    const int sel = r >> 18;                 // 262144 float4 per weight
    off = r & 262143;
    src = (const float4*)(sel == 0 ? wk : sel == 1 ? wq : sel == 2 ? wv : wp);
  }
  const float4 f = src[off];
  ushortx4 o;
  o[0] = f2bfu(f.x); o[1] = f2bfu(f.y); o[2] = f2bfu(f.z); o[3] = f2bfu(f.w);
  dst[i] = o;
}

// ---------------------------------------------------------------------------
// QKV GEMM: C[m,n] = sum_k X[m,k] * W[n,k]   (M=8192, N=1024, K=1024)
// m97 structure + XOR bank swizzle. z=0->Q, z=1->K (both [B,H,T,64]),
// z=2->V^T ([B,H,64,T], vectorized 8B epilogue).
// XCD remap: same m0 (X row-slice) -> same linear%8 -> same XCD L2.
// ---------------------------------------------------------------------------
__global__ __launch_bounds__(256) void gemm_qkv(
    const ushort_t* __restrict__ X,
    const ushort_t* __restrict__ Wq, const ushort_t* __restrict__ Wk,
    const ushort_t* __restrict__ Wv,
    ushort_t* __restrict__ qb, ushort_t* __restrict__ kb, ushort_t* __restrict__ vtb)
{
  // XCD-aware relabel of (m0, n0, z): grid (64,8,3) flat L in [0,1536)
  const int L = (int)(blockIdx.x + 64 * (blockIdx.y + 8 * blockIdx.z));
  const int rr = L & 7, mm = L >> 3;           // mm 0..191
  const int m0 = (rr + 8 * (mm & 7)) * 128;    // 64 m-tiles, same tile -> same rr
  const int rest = mm >> 3;                    // 0..23
  const int n0 = (rest & 7) * 128;
  const int z = rest >> 3;

  const ushort_t* Bm = (z == 0) ? Wq : (z == 1) ? Wk : Wv;
  __shared__ ushort_t Al[128 * 64];
  __shared__ ushort_t Bl[128 * 64];
  const int tid = threadIdx.x;
  const int w = tid >> 6, lane = tid & 63, g = lane >> 4, c = lane & 15;
  const int wm = w >> 1, wn = w & 1;
  const int cswz = c & 7;

  floatx4 acc[4][4];
  const floatx4 zero4 = {0.f, 0.f, 0.f, 0.f};
#pragma unroll
  for (int i = 0; i < 4; ++i)
#pragma unroll
    for (int j = 0; j < 4; ++j) acc[i][j] = zero4;

  const int srow = tid >> 3;
  const int gsw  = ((tid & 7) ^ (srow & 7)) * 8;  // swizzled source chunk (shorts)

  for (int k0 = 0; k0 < 1024; k0 += 64) {
#pragma unroll
    for (int p = 0; p < 4; ++p) {
      const int row = p * 32 + srow;
      gl_lds16(&X [(size_t)(m0 + row) * 1024 + k0 + gsw], &Al[p * 2048 + tid * 8]);
      gl_lds16(&Bm[(size_t)(n0 + row) * 1024 + k0 + gsw], &Bl[p * 2048 + tid * 8]);
    }
    __syncthreads();
#pragma unroll
    for (int kk = 0; kk < 2; ++kk) {
      bf16x8 af[4], bfr[4];
#pragma unroll
      for (int i = 0; i < 4; ++i) {
        const int sw = ((kk * 4 + g) ^ cswz) * 8;
        af[i]  = *reinterpret_cast<const bf16x8*>(&Al[(wm * 64 + i * 16 + c) * 64 + sw]);
        bfr[i] = *reinterpret_cast<const bf16x8*>(&Bl[(wn * 64 + i * 16 + c) * 64 + sw]);
      }
#pragma unroll
      for (int i = 0; i < 4; ++i)
#pragma unroll
        for (int j = 0; j < 4; ++j)
          acc[i][j] = MFMA16(af[i], bfr[j], acc[i][j]);
    }
    __syncthreads();
  }

  // Epilogue: C/D layout row = g*4+r, col = c within each 16x16 tile.
#pragma unroll
  for (int i = 0; i < 4; ++i) {
#pragma unroll
    for (int j = 0; j < 4; ++j) {
      const int mbase = m0 + wm * 64 + i * 16 + g * 4;
      const int n = n0 + wn * 64 + j * 16 + c;
      const int h = n >> 6, d = n & 63;
      if (z == 2) {
        // V^T: [(bb*16+h)*64+d]*2048 + t, 4 consecutive t -> 8B store
        const int bb = mbase >> 11, t = mbase & 2047;
        ushortx4 pk;
#pragma unroll
        for (int r = 0; r < 4; ++r) pk[r] = f2bfu(acc[i][j][r]);
        *reinterpret_cast<ushortx4*>(&vtb[(size_t)((bb * 16 + h) * 64 + d) * 2048 + t]) = pk;
      } else {
        ushort_t* ob = (z == 0) ? qb : kb;
#pragma unroll
        for (int r = 0; r < 4; ++r) {
          const int m = mbase + r;
          const int bb = m >> 11, t = m & 2047;
          ob[(size_t)((bb * 16 + h) * 2048 + t) * 64 + d] = f2bfu(acc[i][j][r]);
        }
      }
    }
  }
}

// ---------------------------------------------------------------------------
// Flash attention (causal), register-resident P^T (R7 body).
// XCD remap: all 16 j-blocks of one (b,h) -> same linear%8 -> same XCD, so
// that (b,h)'s K/V (512 KB) stays L2-resident (8 bh/XCD ~ 4 MB = L2 size).
// Block j of (b,h): q-tiles j and 31-j; wave w owns 16 rows of each.
// Per 128-key staged iter: S^T = K*Q^T (C/D: lane=q, reg=key) -> P^T in
// registers == B-operand of mfma 16x16x16 -> O^T += V^T*P^T.
// No P LDS round-trip; deferred l-reduction.
// ---------------------------------------------------------------------------
__global__ __launch_bounds__(256, 4) void attn_kernel(
    const ushort_t* __restrict__ qbuf, const ushort_t* __restrict__ kbuf,
    const ushort_t* __restrict__ vtbuf, ushort_t* __restrict__ obuf)
{
  // XCD-aware relabel: grid (16,16,4) flat L in [0,1024)
  const int L = (int)(blockIdx.x + 16 * (blockIdx.y + 16 * blockIdx.z));
  const int rr = L & 7, mm = L >> 3;        // mm 0..127
  const int j = mm >> 3;                    // q-tile pair index 0..15
  const int bhl = rr * 8 + (mm & 7);        // 0..63, same bh -> same rr
  const int h = bhl & 15, b = bhl >> 4;

  const int tid = threadIdx.x, w = tid >> 6, lane = tid & 63, g = lane >> 4, c = lane & 15;

  __shared__ ushort_t Kl[128 * 64];       // [key][d], XOR-swizzled 8-chunk rows
  __shared__ ushort_t Vl[64 * 128];       // [d][key], XOR-swizzled 16-chunk rows

  const size_t bh = (size_t)(b * 16 + h);
  const ushort_t* kb_bh = kbuf + bh * 2048 * 64;
  const ushort_t* vt_bh = vtbuf + bh * 64 * 2048;
  const ushort_t* qb_bh = qbuf + bh * 2048 * 64;

  const int rb0 = j * 64 + w * 16;           // grp 0 q-rows (diag tile j)
  const int rb1 = (31 - j) * 64 + w * 16;    // grp 1 q-rows (diag tile 31-j)

  // Q B-frags (x32): B[n=q=lane&15][k=d=quad*8+j]: contiguous 16B loads
  bf16x8 aq0[2], aq1[2];
  {
    const ushort_t* qp0 = qb_bh + (size_t)(rb0 + c) * 64;
    aq0[0] = *reinterpret_cast<const bf16x8*>(qp0 + g * 8);
    aq0[1] = *reinterpret_cast<const bf16x8*>(qp0 + 32 + g * 8);
    const ushort_t* qp1 = qb_bh + (size_t)(rb1 + c) * 64;
    aq1[0] = *reinterpret_cast<const bf16x8*>(qp1 + g * 8);
    aq1[1] = *reinterpret_cast<const bf16x8*>(qp1 + 32 + g * 8);
  }

  // O^T accumulators: [grp][td] tile, lane holds d = td*16+g*4+r, q = rb+c
  floatx4 oacc0[4], oacc1[4];
  float l0 = 0.f, l1 = 0.f;
  const floatx4 zero4 = {0.f, 0.f, 0.f, 0.f};
#pragma unroll
  for (int td = 0; td < 4; ++td) { oacc0[td] = zero4; oacc1[td] = zero4; }

  // staging index helpers
  const int krow_s = tid >> 3;                       // K: 32 rows per p-iter
  const int kgsw   = ((tid & 7) ^ (krow_s & 7)) * 8; // K source chunk (shorts)
  const int vrow_s = tid >> 4;                       // V: 16 rows per p-iter
  const int vgsw   = ((tid & 15) ^ (vrow_s & 15)) * 8;

  const float SCALE = 0.18033688011112042f;  // 0.125 * log2(e)

  const int n128 = (33 - j) >> 1;  // 128-key iters (covers subtiles 0..31-j)
  for (int kt = 0; kt < n128; ++kt) {
    const int key0 = kt * 128;
#pragma unroll
    for (int p = 0; p < 4; ++p) {
      const int kr = p * 32 + krow_s;
      gl_lds16(&kb_bh[(size_t)(key0 + kr) * 64 + kgsw], &Kl[p * 2048 + tid * 8]);
      const int vr = p * 16 + vrow_s;
      gl_lds16(&vt_bh[(size_t)vr * 2048 + key0 + vgsw], &Vl[p * 2048 + tid * 8]);
    }
    __syncthreads();

#pragma unroll
    for (int s = 0; s < 2; ++s) {
      const int ti = 2 * kt + s;       // 64-key subtile index
      const int key0s = ti * 64;
#pragma unroll
      for (int grp = 0; grp < 2; ++grp) {
        const int lim = (grp == 0) ? j : 31 - j;
        if (ti > lim) continue;        // uniform scalar branch
        const int rb = (grp == 0) ? rb0 : rb1;
        const bf16x8 b0 = (grp == 0) ? aq0[0] : aq1[0];
        const bf16x8 b1 = (grp == 0) ? aq0[1] : aq1[1];

        float pv[4][4];
#pragma unroll
        for (int t4 = 0; t4 < 4; ++t4) {
          // S^T tile: A = K-frag (m=key=lane&15 -> row key0s+t4*16+c)
          const int krow = s * 64 + t4 * 16 + c;
          const bf16x8 k0f = *reinterpret_cast<const bf16x8*>(&Kl[krow * 64 + ((g) ^ (c & 7)) * 8]);
          const bf16x8 k1f = *reinterpret_cast<const bf16x8*>(&Kl[krow * 64 + ((4 + g) ^ (c & 7)) * 8]);
          floatx4 sa = zero4;
          sa = MFMA16(k0f, b0, sa);
          sa = MFMA16(k1f, b1, sa);
          // C/D: lane c = q-col, reg r -> key = key0s + t4*16 + g*4 + r
          if (ti == lim) {             // diagonal tile: causal mask
            const int q = rb + c;
#pragma unroll
            for (int r = 0; r < 4; ++r) {
              const int key = key0s + t4 * 16 + g * 4 + r;
              const float e = EXP2F(sa[r] * SCALE);
              pv[t4][r] = (key <= q) ? e : 0.f;
            }
          } else {
#pragma unroll
            for (int r = 0; r < 4; ++r) pv[t4][r] = EXP2F(sa[r] * SCALE);
          }
        }
        // l partial (each lane's 16 values all belong to q = rb+c)
        float lsum = 0.f;
#pragma unroll
        for (int t4 = 0; t4 < 4; ++t4)
          lsum += (pv[t4][0] + pv[t4][1]) + (pv[t4][2] + pv[t4][3]);
        if (grp == 0) l0 += lsum; else l1 += lsum;

        // PV: O^T += V^T * P^T via mfma 16x16x16 (P^T regs ARE the B-frag)
#pragma unroll
        for (int t4 = 0; t4 < 4; ++t4) {
          union { unsigned u[2]; shortx4 v; } pk;
          pk.u[0] = pack_bf2(pv[t4][0], pv[t4][1]);
          pk.u[1] = pack_bf2(pv[t4][2], pv[t4][3]);
          const int cc = s * 8 + t4 * 2 + (g >> 1);       // V key-chunk index
          const int ko = (g & 1) * 4;                      // within-chunk key
#pragma unroll
          for (int td = 0; td < 4; ++td) {
            const shortx4 va = *reinterpret_cast<const shortx4*>(
                &Vl[(td * 16 + c) * 128 + (cc ^ c) * 8 + ko]);
            if (grp == 0) oacc0[td] = MFMA16K16(va, pk.v, oacc0[td]);
            else          oacc1[td] = MFMA16K16(va, pk.v, oacc1[td]);
          }
        }
      }
    }
    __syncthreads();
  }

  // l: reduce across quads (q = c; partial per quad g) then normalize+store
#pragma unroll
  for (int grp = 0; grp < 2; ++grp) {
    float ls = (grp == 0) ? l0 : l1;
    ls += __shfl_xor(ls, 16, 64);
    ls += __shfl_xor(ls, 32, 64);
    const float inv = 1.f / ls;
    const int q = ((grp == 0) ? rb0 : rb1) + c;
    ushort_t* ob = &obuf[((size_t)(b * 2048 + q) * 16 + h) * 64];
#pragma unroll
    for (int td = 0; td < 4; ++td) {
      const floatx4 oa = (grp == 0) ? oacc0[td] : oacc1[td];
      ushortx4 pk;
#pragma unroll
      for (int r = 0; r < 4; ++r) pk[r] = f2bfu(oa[r] * inv);
      *reinterpret_cast<ushortx4*>(&ob[td * 16 + g * 4]) = pk;
    }
  }
}

// ---------------------------------------------------------------------------
// Output projection: out[m,n] = sum_k O[m,k] * Wp[n,k] + bp[n], fp32 out.
// XCD remap as in gemm_qkv.
// ---------------------------------------------------------------------------
__global__ __launch_bounds__(256) void gemm_proj(
    const ushort_t* __restrict__ A, const ushort_t* __restrict__ Wp,
    const float* __restrict__ bias, float* __restrict__ out)
{
  const int L = (int)(blockIdx.x + 64 * blockIdx.y);  // grid (64,8), L in [0,512)
  const int rr = L & 7, mm = L >> 3;                  // mm 0..63
  const int m0 = (rr + 8 * (mm & 7)) * 128;
  const int n0 = (mm >> 3) * 128;

  __shared__ ushort_t Al[128 * 64];
  __shared__ ushort_t Bl[128 * 64];
  const int tid = threadIdx.x;
  const int w = tid >> 6, lane = tid & 63, g = lane >> 4, c = lane & 15;
  const int wm = w >> 1, wn = w & 1;
  const int cswz = c & 7;

  floatx4 acc[4][4];
  const floatx4 zero4 = {0.f, 0.f, 0.f, 0.f};
#pragma unroll
  for (int i = 0; i < 4; ++i)
#pragma unroll
    for (int j = 0; j < 4; ++j) acc[i][j] = zero4;

  const int srow = tid >> 3;
  const int gsw  = ((tid & 7) ^ (srow & 7)) * 8;

  for (int k0 = 0; k0 < 1024; k0 += 64) {
#pragma unroll
    for (int p = 0; p < 4; ++p) {
      const int row = p * 32 + srow;
      gl_lds16(&A [(size_t)(m0 + row) * 1024 + k0 + gsw], &Al[p * 2048 + tid * 8]);
      gl_lds16(&Wp[(size_t)(n0 + row) * 1024 + k0 + gsw], &Bl[p * 2048 + tid * 8]);
    }
    __syncthreads();
#pragma unroll
    for (int kk = 0; kk < 2; ++kk) {
      bf16x8 af[4], bfr[4];
#pragma unroll
      for (int i = 0; i < 4; ++i) {
        const int sw = ((kk * 4 + g) ^ cswz) * 8;
        af[i]  = *reinterpret_cast<const bf16x8*>(&Al[(wm * 64 + i * 16 + c) * 64 + sw]);
        bfr[i] = *reinterpret_cast<const bf16x8*>(&Bl[(wn * 64 + i * 16 + c) * 64 + sw]);
      }
#pragma unroll
      for (int i = 0; i < 4; ++i)
#pragma unroll
        for (int j = 0; j < 4; ++j)
          acc[i][j] = MFMA16(af[i], bfr[j], acc[i][j]);
    }
    __syncthreads();
  }

#pragma unroll
  for (int i = 0; i < 4; ++i) {
#pragma unroll
    for (int j = 0; j < 4; ++j) {
      const int n = n0 + wn * 64 + j * 16 + c;
      const float bv = bias[n];
#pragma unroll
      for (int r = 0; r < 4; ++r) {
        const int m = m0 + wm * 64 + i * 16 + g * 4 + r;
        out[(size_t)m * 1024 + n] = acc[i][j][r] + bv;
      }
    }
  }
}

extern "C" void kernel_launch(void* const* d_in, const int* in_sizes, int n_in,
                              void* d_out, int out_size, void* d_ws, size_t ws_size,
                              hipStream_t stream) {
  const float* x  = (const float*)d_in[0];
  const float* Wk = (const float*)d_in[1];   // input order: x, Wk, Wq, Wv, Wp, bp
  const float* Wq = (const float*)d_in[2];
  const float* Wv = (const float*)d_in[3];
  const float* Wp = (const float*)d_in[4];
  const float* bp = (const float*)d_in[5];
  float* out = (float*)d_out;

  char* ws = (char*)d_ws;
  const size_t SZ_X = (size_t)8192 * 1024 * 2;  // 16 MB bf16
  const size_t SZ_W = (size_t)1024 * 1024 * 2;  //  2 MB bf16
  ushort_t* xb    = (ushort_t*)ws;  ws += SZ_X;  // xb..wpb contiguous (cvt_all dst)
  ushort_t* wkb   = (ushort_t*)ws;  ws += SZ_W;
  ushort_t* wqb   = (ushort_t*)ws;  ws += SZ_W;
  ushort_t* wvb   = (ushort_t*)ws;  ws += SZ_W;
  ushort_t* wpb   = (ushort_t*)ws;  ws += SZ_W;
  ushort_t* qbuf  = (ushort_t*)ws;  ws += SZ_X;
  ushort_t* kbuf  = (ushort_t*)ws;  ws += SZ_X;
  ushort_t* vtbuf = (ushort_t*)ws;  ws += SZ_X;
  ushort_t* obuf  = xb;  // x is consumed by gemm_qkv before attn writes obuf

  cvt_all<<<12288, 256, 0, stream>>>(x, Wk, Wq, Wv, Wp, (ushortx4*)xb);

  gemm_qkv<<<dim3(64, 8, 3), 256, 0, stream>>>(xb, wqb, wkb, wvb, qbuf, kbuf, vtbuf);
  attn_kernel<<<dim3(16, 16, 4), 256, 0, stream>>>(qbuf, kbuf, vtbuf, obuf);
  gemm_proj<<<dim3(64, 8), 256, 0, stream>>>(obuf, wpb, bp, out);
}